// Round 10
// baseline (43.455 us; speedup 1.0000x reference)
//
#include <hip/hip_runtime.h>
#include <math.h>

#define NEGVF (-1e30f)
#define CTC_T 512
#define CTC_C 256
#define CTC_L 128
#define BLANKC (CTC_C - 1)

typedef float f4 __attribute__((ext_vector_type(4)));

#if __has_builtin(__builtin_amdgcn_exp2f)
__device__ __forceinline__ float fexp2(float x) { return __builtin_amdgcn_exp2f(x); }
#else
__device__ __forceinline__ float fexp2(float x) { return exp2f(x); }
#endif
#if __has_builtin(__builtin_amdgcn_logf)
__device__ __forceinline__ float flog2(float x) { return __builtin_amdgcn_logf(x); }
#else
__device__ __forceinline__ float flog2(float x) { return log2f(x); }
#endif

// log2-domain logaddexp (final combine only)
__device__ __forceinline__ float lae2(float a, float b) {
    float m = fmaxf(a, b);
    float n = fminf(a, b);
    return m + flog2(1.0f + fexp2(n - m));
}

// Whole-wave shift-up-by-1 at VALU speed (lane 0 receives 0).
__device__ __forceinline__ float dpp_shr1_f(float x) {
    return __int_as_float(__builtin_amdgcn_update_dpp(
        0, __float_as_int(x), 0x138, 0xF, 0xF, true));
}
__device__ __forceinline__ int dpp_shr1_i(int x) {
    return __builtin_amdgcn_update_dpp(0, x, 0x138, 0xF, 0xF, true);
}

// One wave per batch element. Lane k owns states 4k..4k+3; lane 63 also owns
// s=256 (a4). Even states = blanks. State 4k+1 -> label 2k; 4k+3 -> 2k+1.
//
// Linear-domain recursion a' = (a + s1 + s2) * p with per-lane scale E,
// renormalized per 8-step body (dead lanes adopt lane 0's E); cross-lane a3
// via DPP, rescaled by ldexp at consume.
//
// Row access: ONE coalesced global_load_dwordx4 per row per lane (whole 1 KB
// row in one VMEM instr) into triple-buffered f4 registers, staged 2 bodies
// ahead (counted vmcnt, never drained). Per step, the row is pushed through a
// 4-slot LDS buffer (ds_write_b128 + 3 ds_read gathers) TWO steps ahead of
// consumption — the divergent gather moves off the TA/L2 path (r8's ~100
// cyc/step) onto the LDS pipe with ~2 steps of latency slack.
__global__ __launch_bounds__(64) void ctc_fwd_kernel(
    const int* __restrict__ y_true,    // [B, L]
    const float* __restrict__ y_pred,  // [B, T, C]
    const int* __restrict__ in_len,    // [B]
    const int* __restrict__ lab_len,   // [B]
    float* __restrict__ out)           // [B]
{
    __shared__ float rowbufF[4][CTC_C];   // 4 KB, slot = (t)&3
    __shared__ float sh[2 * CTC_L + 1];

    const int b = blockIdx.x;
    const int k = threadIdx.x;  // 0..63

    const float* __restrict__ ybase = y_pred + (size_t)b * CTC_T * CTC_C;
    const uint64_t ybase_u = (uint64_t)(uintptr_t)ybase;
    const int* __restrict__ yt = y_true + (size_t)b * CTC_L;

    const int l0 = yt[2 * k];
    const int l1 = yt[2 * k + 1];
    const int lm1 = __shfl_up(l1, 1);  // yt[2k-1] for k>0 (one-time)
    const float sk1f = ((k > 0) && (l0 != lm1) && (l0 != BLANKC)) ? 1.0f : 0.0f;
    const float sk3f = ((l1 != l0) && (l1 != BLANKC)) ? 1.0f : 0.0f;

    int inl = in_len[b];
    if (inl > CTC_T) inl = CTC_T;
    const int nsteps = inl - 1;  // update steps t = 1..nsteps (may be <= 0)

    // t = 0 init (linear domain) — plain loads, consumed before any asm loads
    float pb0 = ybase[BLANKC];
    float p00 = ybase[l0];
    float a0 = (k == 0) ? pb0 : 0.0f;
    float a1 = (k == 0) ? p00 : 0.0f;
    float a2 = 0.0f, a3 = 0.0f, a4 = 0.0f;
    int   E  = 0;        // stored * 2^E == true alpha
    float pm3raw = 0.0f; // neighbor a3 in flight (raw, neighbor's scale)

    const int v_off4 = k << 4;  // coalesced: lane k -> bytes [16k, 16k+16)

    // triple-buffered row registers (ALL indices compile-time constants)
    f4 bufrow[3][8];

    // SGPR row-block bases for fast staging (advanced once per body)
    uint64_t baseA = ybase_u + 1024;      // row t0
    uint64_t baseB = baseA + 4096;        // row t0+4

#define LOAD4(dst, rb) \
    asm volatile("global_load_dwordx4 %0, %1, %2" \
                 : "=v"(dst) : "v"(v_off4), "s"(rb) : "memory")
#define LOAD4O(dst, rb, OFF) \
    asm volatile("global_load_dwordx4 %0, %1, %2 offset:" OFF \
                 : "=v"(dst) : "v"(v_off4), "s"(rb) : "memory")

#define STAGE_FAST(stg) { \
    LOAD4O(bufrow[stg][0], baseA, "0");    LOAD4O(bufrow[stg][1], baseA, "1024"); \
    LOAD4O(bufrow[stg][2], baseA, "2048"); LOAD4O(bufrow[stg][3], baseA, "3072"); \
    LOAD4O(bufrow[stg][4], baseB, "0");    LOAD4O(bufrow[stg][5], baseB, "1024"); \
    LOAD4O(bufrow[stg][6], baseB, "2048"); LOAD4O(bufrow[stg][7], baseB, "3072"); }

#define STGS(stg, r, t0) { \
    int rr = (t0) + (r); if (rr > nsteps) rr = nsteps; \
    uint64_t rb = ybase_u + (uint64_t)rr * (CTC_C * 4); \
    LOAD4(bufrow[stg][r], rb); }
#define STAGE_SLOW(stg, t0) { \
    STGS(stg, 0, t0) STGS(stg, 1, t0) STGS(stg, 2, t0) STGS(stg, 3, t0) \
    STGS(stg, 4, t0) STGS(stg, 5, t0) STGS(stg, 6, t0) STGS(stg, 7, t0) }

    // LDS pipeline registers: C (consume this step), M (next), N (in flight)
    float pbC, p0C, p1C, pbM, p0M, p1M, pbN, p0N, p1N;

// push row srcf4 into LDS slot S and gather the 3 values into named regs
#define PREPX(srcf4, S, pbX, p0X, p1X) { \
    ((f4*)rowbufF[S])[k] = (srcf4); \
    pbX = rowbufF[S][BLANKC]; \
    p0X = rowbufF[S][l0]; \
    p1X = rowbufF[S][l1]; }

// one step: prep t+2 (slot compile-time), consume C, rotate C<-M<-N
#define SSTEP(dX, srcf4, S) { \
    PREPX(srcf4, S, pbN, p0N, p1N); \
    float pmu = ldexpf(pm3raw, dX); \
    float a3n = fmaf(sk3f, a1, a3 + a2) * p1C; \
    pm3raw = dpp_shr1_f(a3n); \
    float a0n = (a0 + pmu) * pbC; \
    float a1n = fmaf(sk1f, pmu, a1 + a0) * p0C; \
    float a2n = (a2 + a1) * pbC; \
    a4 = (a4 + a3) * pbC; \
    a0 = a0n; a1 = a1n; a2 = a2n; a3 = a3n; \
    pbC = pbM; p0C = p0M; p1C = p1M; \
    pbM = pbN; p0M = p0N; p1M = p1N; }

// body j: consume buffer cur, next body's buffer nxt, stage into stg.
// Step r prepares row t+2: r=0..5 -> bufrow[cur][r+2], r=6 -> nxt[0] (after
// vmcnt(15)), r=7 -> nxt[1] (after vmcnt(14)). Slot(t+2) = (r+3)&3 since
// tbase ≡ 1 (mod 8).
#define BODY(cur, nxt, stg) { \
    int t0s = tbase + 16; \
    if (t0s + 7 <= nsteps) { STAGE_FAST(stg); } \
    else                   { STAGE_SLOW(stg, t0s); } \
    baseA += 8192; baseB += 8192; \
    int EnbOld = dpp_shr1_i(E); \
    float m = fmaxf(fmaxf(fmaxf(a0, a1), fmaxf(a2, a3)), a4); \
    float mm = m * 0x1p64f; \
    int exm = (__float_as_int(mm) >> 23) & 0xff; \
    bool dead = (exm == 0); \
    int dd = dead ? 0 : (191 - exm); \
    a0 = ldexpf(a0, dd); a1 = ldexpf(a1, dd); a2 = ldexpf(a2, dd); \
    a3 = ldexpf(a3, dd); a4 = ldexpf(a4, dd); \
    E -= dd; \
    int E0 = __builtin_amdgcn_readfirstlane(E); \
    E = dead ? E0 : E; \
    int Enb = dpp_shr1_i(E); \
    int dnb  = Enb - E; \
    int dadj = EnbOld - E; \
    asm volatile("s_waitcnt vmcnt(16)" ::: "memory"); \
    __builtin_amdgcn_sched_barrier(0); \
    if (tbase + 7 <= nsteps) { \
        SSTEP(dadj, bufrow[cur][2], 3) \
        SSTEP(dnb,  bufrow[cur][3], 0) \
        SSTEP(dnb,  bufrow[cur][4], 1) \
        SSTEP(dnb,  bufrow[cur][5], 2) \
        SSTEP(dnb,  bufrow[cur][6], 3) \
        SSTEP(dnb,  bufrow[cur][7], 0) \
        asm volatile("s_waitcnt vmcnt(15)" ::: "memory"); \
        SSTEP(dnb,  bufrow[nxt][0], 1) \
        asm volatile("s_waitcnt vmcnt(14)" ::: "memory"); \
        SSTEP(dnb,  bufrow[nxt][1], 2) \
    } else { \
        int rem = nsteps - tbase; \
        SSTEP(dadj, bufrow[cur][2], 3) \
        if (rem > 0) { SSTEP(dnb, bufrow[cur][3], 0) } \
        if (rem > 1) { SSTEP(dnb, bufrow[cur][4], 1) } \
        if (rem > 2) { SSTEP(dnb, bufrow[cur][5], 2) } \
        if (rem > 3) { SSTEP(dnb, bufrow[cur][6], 3) } \
        if (rem > 4) { SSTEP(dnb, bufrow[cur][7], 0) } \
        if (rem > 5) { asm volatile("s_waitcnt vmcnt(15)" ::: "memory"); \
                       SSTEP(dnb, bufrow[nxt][0], 1) } \
        if (rem > 6) { asm volatile("s_waitcnt vmcnt(14)" ::: "memory"); \
                       SSTEP(dnb, bufrow[nxt][1], 2) } \
    } \
}

    const int nb2 = (nsteps > 0) ? ((nsteps + 7) >> 3) : 0;
    int tbase = 1;

    if (nb2 >= 1) {
        __builtin_amdgcn_sched_barrier(0);  // fence init loads from asm region
        if (8 <= nsteps)  { STAGE_FAST(0); } else { STAGE_SLOW(0, 1); }
        baseA += 8192; baseB += 8192;
        if (16 <= nsteps) { STAGE_FAST(1); } else { STAGE_SLOW(1, 9); }
        baseA += 8192; baseB += 8192;
        // prime LDS pipeline: t=1 (slot 1) and t=2 (slot 2)
        asm volatile("s_waitcnt vmcnt(14)" ::: "memory");
        __builtin_amdgcn_sched_barrier(0);
        PREPX(bufrow[0][0], 1, pbC, p0C, p1C);
        PREPX(bufrow[0][1], 2, pbM, p0M, p1M);
        int j = 0;
        for (;;) {
            BODY(0, 1, 2); tbase += 8; if (++j >= nb2) break;
            BODY(1, 2, 0); tbase += 8; if (++j >= nb2) break;
            BODY(2, 0, 1); tbase += 8; if (++j >= nb2) break;
        }
    }

    // convert to absolute log2 (clamp so dead states act like NEG, not -inf)
    float l0v = fmaxf(flog2(a0) + (float)E, NEGVF);
    float l1v = fmaxf(flog2(a1) + (float)E, NEGVF);
    float l2v = fmaxf(flog2(a2) + (float)E, NEGVF);
    float l3v = fmaxf(flog2(a3) + (float)E, NEGVF);
    float l4v = fmaxf(flog2(a4) + (float)E, NEGVF);

    // gather final log2-alphas, compute loss on lane 0
    sh[4 * k + 0] = l0v;
    sh[4 * k + 1] = l1v;
    sh[4 * k + 2] = l2v;
    sh[4 * k + 3] = l3v;
    if (k == 63) sh[256] = l4v;
    __syncthreads();
    if (k == 0) {
        int ll = lab_len[b];
        if (ll < 1) ll = 1;
        if (ll > CTC_L) ll = CTC_L;
        float ea = sh[2 * ll - 1];
        float eb = sh[2 * ll];
        // restore per-emit log-softmax constant (log2 of softmax denominator)
        int cnt = 1 + (nsteps > 0 ? nsteps : 0);
        const float LSE2 = flog2(1.0f + (float)CTC_C * 1e-7f);
        out[b] = -0.69314718055994530942f * (lae2(ea, eb) - (float)cnt * LSE2);
    }
#undef LOAD4
#undef LOAD4O
#undef STAGE_FAST
#undef STGS
#undef STAGE_SLOW
#undef PREPX
#undef SSTEP
#undef BODY
}

extern "C" void kernel_launch(void* const* d_in, const int* in_sizes, int n_in,
                              void* d_out, int out_size, void* d_ws, size_t ws_size,
                              hipStream_t stream) {
    (void)n_in; (void)d_ws; (void)ws_size; (void)out_size;
    const int* y_true = (const int*)d_in[0];
    const float* y_pred = (const float*)d_in[1];
    const int* in_len = (const int*)d_in[2];
    const int* lab_len = (const int*)d_in[3];
    float* out = (float*)d_out;
    const int B = in_sizes[2];  // input_length has B elements
    ctc_fwd_kernel<<<B, 64, 0, stream>>>(y_true, y_pred, in_len, lab_len, out);
}

// Round 11
// 38.843 us; speedup vs baseline: 1.1187x; 1.1187x over previous
//
#include <hip/hip_runtime.h>
#include <math.h>

#define NEGVF (-1e30f)
#define CTC_T 512
#define CTC_C 256
#define CTC_L 128
#define BLANKC (CTC_C - 1)

#if __has_builtin(__builtin_amdgcn_exp2f)
__device__ __forceinline__ float fexp2(float x) { return __builtin_amdgcn_exp2f(x); }
#else
__device__ __forceinline__ float fexp2(float x) { return exp2f(x); }
#endif
#if __has_builtin(__builtin_amdgcn_logf)
__device__ __forceinline__ float flog2(float x) { return __builtin_amdgcn_logf(x); }
#else
__device__ __forceinline__ float flog2(float x) { return log2f(x); }
#endif

__device__ __forceinline__ float lae2(float a, float b) {
    float m = fmaxf(a, b);
    float n = fminf(a, b);
    return m + flog2(1.0f + fexp2(n - m));
}

// Whole-wave shift-up-by-1 at VALU speed (lane 0 receives 0).
__device__ __forceinline__ float dpp_shr1_f(float x) {
    return __int_as_float(__builtin_amdgcn_update_dpp(
        0, __float_as_int(x), 0x138, 0xF, 0xF, true));
}
__device__ __forceinline__ int dpp_shr1_i(int x) {
    return __builtin_amdgcn_update_dpp(0, x, 0x138, 0xF, 0xF, true);
}

// 4 waves per block (1 block per batch element):
//   wave 0            = consumer: runs the linear-domain CTC recursion.
//   waves 1..3        = producers: body bj (8 steps) handled by wave 1+(bj%3):
//                       issue 24 divergent global loads in period bj,
//                       vmcnt(0)+LDS-write in period bj+1 (>= 1 period slack),
//                       consumer reads in period bj+3 (2 barriers later).
// One raw s_barrier per period; all waves execute nb2+3 periods.
// LDS ring: 4 slots x 8 steps x {pb,p0,p1} x 64 lanes (24.5 KB).
// Slot audit per period jj: consumer reads (jj-3)&3, consumer end-prime reads
// (jj-2)&3, producer writes (jj-1)&3 -- pairwise distinct, all writes
// barrier-separated from reads.
__global__ __launch_bounds__(256) void ctc_fwd_kernel(
    const int* __restrict__ y_true,    // [B, L]
    const float* __restrict__ y_pred,  // [B, T, C]
    const int* __restrict__ in_len,    // [B]
    const int* __restrict__ lab_len,   // [B]
    float* __restrict__ out)           // [B]
{
    __shared__ float ring[4][8][3][64];   // 24.5 KB staging ring
    __shared__ float sh[2 * CTC_L + 1];

    const int b   = blockIdx.x;
    const int tid = threadIdx.x;
    const int wid = tid >> 6;   // 0..3
    const int k   = tid & 63;   // lane

    const float* __restrict__ ybase = y_pred + (size_t)b * CTC_T * CTC_C;
    const uint64_t ybase_u = (uint64_t)(uintptr_t)ybase;
    const int* __restrict__ yt = y_true + (size_t)b * CTC_L;

    const int l0 = yt[2 * k];
    const int l1 = yt[2 * k + 1];
    const int lm1 = __shfl_up(l1, 1);  // wave-local; same values in every wave
    const float sk1f = ((k > 0) && (l0 != lm1) && (l0 != BLANKC)) ? 1.0f : 0.0f;
    const float sk3f = ((l1 != l0) && (l1 != BLANKC)) ? 1.0f : 0.0f;

    int inl = in_len[b];
    if (inl > CTC_T) inl = CTC_T;
    const int nsteps = inl - 1;                       // steps t = 1..nsteps
    const int nb2 = (nsteps > 0) ? ((nsteps + 7) >> 3) : 0;

    // t = 0 init (linear domain); meaningful on wave 0 only
    float pb0 = ybase[BLANKC];
    float p00 = ybase[l0];
    float a0 = (k == 0) ? pb0 : 0.0f;
    float a1 = (k == 0) ? p00 : 0.0f;
    float a2 = 0.0f, a3 = 0.0f, a4 = 0.0f;
    int   E  = 0;
    float pm3raw = 0.0f;

    // per-lane gather byte offsets
    int v_ofb = BLANKC * 4;
    int v_of0 = l0 * 4;
    int v_of1 = l1 * 4;

#define LOAD1(dst, voff, rb) \
    asm volatile("global_load_dword %0, %1, %2" \
                 : "=v"(dst) : "v"(voff), "s"(rb) : "memory")

    if (nb2 >= 1) {
        if (wid == 0) {
            // ---------------- consumer ----------------
            float pbC = 0, p0C = 0, p1C = 0, pbM = 0, p0M = 0, p1M = 0;
            float pbN = 0, p0N = 0, p1N = 0;

#define RD(rp_, rr, A, Bv, Cv) { \
    A  = (rp_)[(rr) * 192 + k]; \
    Bv = (rp_)[(rr) * 192 + 64 + k]; \
    Cv = (rp_)[(rr) * 192 + 128 + k]; }

#define CARITH(dX) { \
    float pmu = ldexpf(pm3raw, dX); \
    float a3n = fmaf(sk3f, a1, a3 + a2) * p1C; \
    pm3raw = dpp_shr1_f(a3n); \
    float a0n = (a0 + pmu) * pbC; \
    float a1n = fmaf(sk1f, pmu, a1 + a0) * p0C; \
    float a2n = (a2 + a1) * pbC; \
    a4 = (a4 + a3) * pbC; \
    a0 = a0n; a1 = a1n; a2 = a2n; a3 = a3n; }

#define ROT2 { pbC = pbM; p0C = p0M; p1C = p1M; pbM = pbN; p0M = p0N; p1M = p1N; }
#define ROT1 { pbC = pbM; p0C = p0M; p1C = p1M; }

            for (int jj = 0; jj < nb2 + 3; ++jj) {
                __builtin_amdgcn_s_barrier();
                int cj = jj - 3;
                if (cj < 0) continue;
                int tbase = 1 + 8 * cj;
                int rem = nsteps - tbase;
                const float* rp = (const float*)&ring[cj & 3][0][0][0];
                if (cj == 0) {  // first body: prime r0,r1
                    RD(rp, 0, pbC, p0C, p1C);
                    RD(rp, 1, pbM, p0M, p1M);
                }
                // per-body renorm
                int EnbOld = dpp_shr1_i(E);
                float m = fmaxf(fmaxf(fmaxf(a0, a1), fmaxf(a2, a3)), a4);
                float mm = m * 0x1p64f;
                int exm = (__float_as_int(mm) >> 23) & 0xff;
                bool dead = (exm == 0);
                int dd = dead ? 0 : (191 - exm);
                a0 = ldexpf(a0, dd); a1 = ldexpf(a1, dd); a2 = ldexpf(a2, dd);
                a3 = ldexpf(a3, dd); a4 = ldexpf(a4, dd);
                E -= dd;
                int E0 = __builtin_amdgcn_readfirstlane(E);
                E = dead ? E0 : E;
                int Enb = dpp_shr1_i(E);
                int dnb  = Enb - E;
                int dadj = EnbOld - E;
                // 8 steps, reads prefetched 2 ahead within the slot
                { RD(rp, 2, pbN, p0N, p1N); CARITH(dadj); ROT2 }
                if (rem > 0) { RD(rp, 3, pbN, p0N, p1N); CARITH(dnb); ROT2 }
                if (rem > 1) { RD(rp, 4, pbN, p0N, p1N); CARITH(dnb); ROT2 }
                if (rem > 2) { RD(rp, 5, pbN, p0N, p1N); CARITH(dnb); ROT2 }
                if (rem > 3) { RD(rp, 6, pbN, p0N, p1N); CARITH(dnb); ROT2 }
                if (rem > 4) { RD(rp, 7, pbN, p0N, p1N); CARITH(dnb); ROT2 }
                if (rem > 5) { CARITH(dnb); ROT1 }
                if (rem > 6) { CARITH(dnb); }
                // prime next body's r0,r1 (slot written >= 1 period ago)
                if (cj + 1 < nb2) {
                    const float* np = (const float*)&ring[(cj + 1) & 3][0][0][0];
                    RD(np, 0, pbC, p0C, p1C);
                    RD(np, 1, pbM, p0M, p1M);
                }
            }
#undef RD
#undef CARITH
#undef ROT2
#undef ROT1
        } else {
            // ---------------- producers ----------------
            const int p = wid - 1;  // 0..2
            float gpb[8], gp0[8], gp1[8];

#define PROW(r_, t0_) { \
    int rr = (t0_) + (r_); if (rr > nsteps) rr = nsteps; \
    uint64_t rb = ybase_u + (uint64_t)rr * (CTC_C * 4); \
    LOAD1(gpb[r_], v_ofb, rb); \
    LOAD1(gp0[r_], v_of0, rb); \
    LOAD1(gp1[r_], v_of1, rb); }

#define PISSUE(bj_) { \
    int t0 = 1 + 8 * (bj_); \
    PROW(0, t0) PROW(1, t0) PROW(2, t0) PROW(3, t0) \
    PROW(4, t0) PROW(5, t0) PROW(6, t0) PROW(7, t0) }

#define WROW(wp_, r_) { \
    (wp_)[(r_) * 192 + k]        = gpb[r_]; \
    (wp_)[(r_) * 192 + 64 + k]   = gp0[r_]; \
    (wp_)[(r_) * 192 + 128 + k]  = gp1[r_]; }

#define PCOMPLETE(bc_) { \
    asm volatile("s_waitcnt vmcnt(0)" ::: "memory"); \
    __builtin_amdgcn_sched_barrier(0); \
    float* wp = (float*)&ring[(bc_) & 3][0][0][0]; \
    WROW(wp, 0) WROW(wp, 1) WROW(wp, 2) WROW(wp, 3) \
    WROW(wp, 4) WROW(wp, 5) WROW(wp, 6) WROW(wp, 7) \
    asm volatile("s_waitcnt lgkmcnt(0)" ::: "memory"); }

            for (int jj = 0; jj < nb2 + 3; ++jj) {
                __builtin_amdgcn_s_barrier();
                int bc = jj - 1;  // complete body issued 1-2 periods ago
                if (bc >= 0 && bc < nb2 && (bc % 3) == p) PCOMPLETE(bc);
                if (jj == 0 && p == 0) PISSUE(0);     // body 0 special-cased
                int bi = jj + 1;                       // issue 2 periods early
                if (bi < nb2 && (bi % 3) == p) PISSUE(bi);
            }
#undef PROW
#undef PISSUE
#undef WROW
#undef PCOMPLETE
        }
    }

    // convert to absolute log2 (clamp so dead states act like NEG, not -inf)
    float l0v = fmaxf(flog2(a0) + (float)E, NEGVF);
    float l1v = fmaxf(flog2(a1) + (float)E, NEGVF);
    float l2v = fmaxf(flog2(a2) + (float)E, NEGVF);
    float l3v = fmaxf(flog2(a3) + (float)E, NEGVF);
    float l4v = fmaxf(flog2(a4) + (float)E, NEGVF);

    if (wid == 0) {
        sh[4 * k + 0] = l0v;
        sh[4 * k + 1] = l1v;
        sh[4 * k + 2] = l2v;
        sh[4 * k + 3] = l3v;
        if (k == 63) sh[256] = l4v;
    }
    __syncthreads();
    if (tid == 0) {
        int ll = lab_len[b];
        if (ll < 1) ll = 1;
        if (ll > CTC_L) ll = CTC_L;
        float ea = sh[2 * ll - 1];
        float eb = sh[2 * ll];
        int cnt = 1 + (nsteps > 0 ? nsteps : 0);
        const float LSE2 = flog2(1.0f + (float)CTC_C * 1e-7f);
        out[b] = -0.69314718055994530942f * (lae2(ea, eb) - (float)cnt * LSE2);
    }
#undef LOAD1
}

extern "C" void kernel_launch(void* const* d_in, const int* in_sizes, int n_in,
                              void* d_out, int out_size, void* d_ws, size_t ws_size,
                              hipStream_t stream) {
    (void)n_in; (void)d_ws; (void)ws_size; (void)out_size;
    const int* y_true = (const int*)d_in[0];
    const float* y_pred = (const float*)d_in[1];
    const int* in_len = (const int*)d_in[2];
    const int* lab_len = (const int*)d_in[3];
    float* out = (float*)d_out;
    const int B = in_sizes[2];  // input_length has B elements
    ctc_fwd_kernel<<<B, 256, 0, stream>>>(y_true, y_pred, in_len, lab_len, out);
}